// Round 10
// baseline (212.766 us; speedup 1.0000x reference)
//
#include <hip/hip_runtime.h>
#include <cmath>

typedef unsigned short u16;
typedef unsigned int u32;
typedef __bf16 bf16x8 __attribute__((ext_vector_type(8)));
typedef float f32x4 __attribute__((ext_vector_type(4)));

#define D_MODEL 1024
#define NHEAD 16
#define HD 64
#define SEQ 2048
#define BATCH 2
#define M_TOK 4096      // BATCH*SEQ
#define N_QKV 3072

#define LOG2E 1.4426950408889634f
#define SOFTMAX_SHIFT 11.541560327111707f   // 8 * log2(e)

// float -> bf16 round-to-nearest-even (matches HW cvt)
__device__ __forceinline__ u16 f2bf(float f) {
    u32 u = __float_as_uint(f);
    u32 r = (u + 0x7fffu + ((u >> 16) & 1u)) >> 16;
    return (u16)r;
}

__device__ __forceinline__ float bf2f(u16 v) {
    return __uint_as_float(((u32)v) << 16);
}

// pack two fp32 -> two bf16 in one b32 (a in low half)
__device__ __forceinline__ u32 pack_bf(float a, float b) {
#if __has_builtin(__builtin_amdgcn_cvt_pk_bf16_f32)
    typedef __bf16 bf16x2_t __attribute__((ext_vector_type(2)));
    union { bf16x2_t v; u32 u; } c;
    c.v = __builtin_amdgcn_cvt_pk_bf16_f32(a, b);
    return c.u;
#else
    u32 ua = __float_as_uint(a) + 0x8000u;
    u32 ub = __float_as_uint(b) + 0x8000u;
    return __builtin_amdgcn_perm(ub, ua, 0x07060302u);
#endif
}

__device__ __forceinline__ bf16x8 ld_bf8(const u16* p) {
    return *(const bf16x8*)p;
}

__device__ __forceinline__ bf16x8 as_bf8(int4 v) {
    union { int4 i; bf16x8 b; } u; u.i = v; return u.b;
}

__device__ __forceinline__ f32x4 mfma16(bf16x8 a, bf16x8 b, f32x4 c) {
    return __builtin_amdgcn_mfma_f32_16x16x32_bf16(a, b, c, 0, 0, 0);
}

// async global->LDS, 16 B per lane. LDS dest = wave-uniform base + lane*16.
__device__ __forceinline__ void gload_lds16(const u16* g, u16* l) {
    __builtin_amdgcn_global_load_lds(
        (const __attribute__((address_space(1))) void*)g,
        (__attribute__((address_space(3))) void*)l, 16, 0, 0);
}

// #V-columns in [0,x) of the interleaved [q|k|v]x192 layout
__device__ __forceinline__ int Gv(int x) {
    int q = x / 192, rm = x - q * 192;
    int e = rm - 128;
    return q * 64 + (e > 0 ? e : 0);
}

// ---------------- fused prep: cast x + transpose-cast W_qkv + transpose-cast W_out ----------------
// region A: blocks [0,1024)            cast x fp32->bf16 (float4 grid-stride)
// region B: blocks [1024, 1024+3072)   transpose W_qkv [1024][3072] -> [3072][1024]
// region C: blocks [4096, 4096+1024)   transpose W_out [1024][1024] -> [1024][1024]^T
__global__ __launch_bounds__(256) void prep_kernel(
    const float* __restrict__ x, u16* __restrict__ Xb,
    const float* __restrict__ W_qkv, u16* __restrict__ Wqkvt,
    const float* __restrict__ W_out, u16* __restrict__ Woutt)
{
    int blk = blockIdx.x;
    if (blk < 1024) {
        int n4 = M_TOK * D_MODEL / 4;
        int i = blk * 256 + threadIdx.x;
        int stride = 1024 * 256;
        for (; i < n4; i += stride) {
            float4 v = ((const float4*)x)[i];
            ushort4 o;
            o.x = f2bf(v.x); o.y = f2bf(v.y); o.z = f2bf(v.z); o.w = f2bf(v.w);
            ((ushort4*)Xb)[i] = o;
        }
        return;
    }
    __shared__ float tile[32][33];
    const float* in;
    u16* out;
    int ROWS, COLS, bx, by;
    if (blk < 4096) {
        int b = blk - 1024;            // transpose W_qkv: grid (96,32)
        bx = b % 96; by = b / 96;
        in = W_qkv; out = Wqkvt; ROWS = 1024; COLS = 3072;
    } else {
        int b = blk - 4096;            // transpose W_out: grid (32,32)
        bx = b & 31; by = b >> 5;
        in = W_out; out = Woutt; ROWS = 1024; COLS = 1024;
    }
    int c0 = bx * 32, r0 = by * 32;
    int tx = threadIdx.x & 31, ty = threadIdx.x >> 5;   // 32x8
#pragma unroll
    for (int i = 0; i < 32; i += 8)
        tile[ty + i][tx] = in[(size_t)(r0 + ty + i) * COLS + c0 + tx];
    __syncthreads();
#pragma unroll
    for (int i = 0; i < 32; i += 8)
        out[(size_t)(c0 + ty + i) * ROWS + r0 + tx] = f2bf(tile[tx][ty + i]);
}

// ---------------- QKV GEMM, dbuf K-loop: C[4096][3072] = A * Bt^T + bias ----------------
// Single barrier per K-step; prefetch of k0+32 drains under current tile's MFMA.
// Epilogue: Q [bh][s][d] (x0.125), K [bh][s][d] direct; V bounced through an
// LDS tile then dumped as coalesced 16B stores into Vp[bh][d][s'],
// s' = within-128 permutation matching the attn PV k-slot order.
__global__ __launch_bounds__(256) void gemm_qkv_kernel(
    const u16* __restrict__ A, const u16* __restrict__ Bt, const float* __restrict__ bias,
    u16* __restrict__ Qb, u16* __restrict__ Kb, u16* __restrict__ Vp)
{
    __shared__ u16 lA[2][128 * 32];
    __shared__ u16 lB[2][128 * 32];
    __shared__ u16 vtile[64 * 132];   // [vloc][sp], stride 132 -> 2-way banks (free)
    int w = threadIdx.x >> 6, l = threadIdx.x & 63;
    int col = l & 15, quad = l >> 4;
    int wm = w >> 1, wn = w & 1;
    int m0 = blockIdx.x * 128;
    int n0 = blockIdx.y * 128;
    int lrow = l >> 2;            // 0..15 within a 16-row slab
    int lcol = (l & 3) * 8;       // 0/8/16/24

    // prologue: stage k0=0 into buf 0
#pragma unroll
    for (int i = 0; i < 2; i++) {
        int slab = w * 32 + i * 16;
        gload_lds16(A  + (size_t)(m0 + slab + lrow) * 1024 + lcol, lA[0] + slab * 32);
        gload_lds16(Bt + (size_t)(n0 + slab + lrow) * 1024 + lcol, lB[0] + slab * 32);
    }

    f32x4 acc[4][4] = {};
    for (int it = 0; it < 32; ++it) {
        int cur = it & 1;
        __syncthreads();             // drains prefetch of buf `cur`
        if (it + 1 < 32) {
            int k0 = (it + 1) * 32;
            int nb = cur ^ 1;
#pragma unroll
            for (int i = 0; i < 2; i++) {
                int slab = w * 32 + i * 16;
                gload_lds16(A  + (size_t)(m0 + slab + lrow) * 1024 + k0 + lcol, lA[nb] + slab * 32);
                gload_lds16(Bt + (size_t)(n0 + slab + lrow) * 1024 + k0 + lcol, lB[nb] + slab * 32);
            }
        }
        bf16x8 af[4], bfr[4];
#pragma unroll
        for (int i = 0; i < 4; i++)
            af[i] = ld_bf8(lA[cur] + (wm * 64 + i * 16 + col) * 32 + quad * 8);
#pragma unroll
        for (int j = 0; j < 4; j++)
            bfr[j] = ld_bf8(lB[cur] + (wn * 64 + j * 16 + col) * 32 + quad * 8);
#pragma unroll
        for (int i = 0; i < 4; i++)
#pragma unroll
            for (int j = 0; j < 4; j++)
                acc[i][j] = mfma16(af[i], bfr[j], acc[i][j]);
    }

    int s0 = m0 & 2047;
    int bblk = m0 >> 11;
#pragma unroll
    for (int i = 0; i < 4; i++) {
#pragma unroll
        for (int j = 0; j < 4; j++) {
            int cc = n0 + wn * 64 + j * 16 + col;   // 0..3071
            int h = cc / 192;
            int within = cc - h * 192;
            int ww = within >> 6;                   // 0=q 1=k 2=v
            int d = within & 63;
            int vloc = Gv(cc) - Gv(n0);
            float bv = bias[cc];
#pragma unroll
            for (int r = 0; r < 4; r++) {
                int sloc = wm * 64 + i * 16 + quad * 4 + r;   // 0..127
                int s = s0 + sloc;
                int bh = bblk * NHEAD + h;
                float val = acc[i][j][r] + bv;
                if (ww == 0)      Qb[(size_t)(bh * SEQ + s) * HD + d] = f2bf(val * 0.125f);
                else if (ww == 1) Kb[(size_t)(bh * SEQ + s) * HD + d] = f2bf(val);
                else {
                    int sp = (sloc & ~31) | ((sloc & 12) << 1) | (((sloc >> 4) & 1) << 2) | (sloc & 3);
                    vtile[vloc * 132 + sp] = f2bf(val);
                }
            }
        }
    }
    __syncthreads();
    // coalesced V dump: 16B chunks along s'
    int vcols = Gv(n0 + 128) - Gv(n0);
    int gbase = Gv(n0);
    for (int c = threadIdx.x; c < vcols * 16; c += 256) {
        int vloc = c >> 4, gi = c & 15;
        int av = gbase + vloc;
        int h = av >> 6, d = av & 63;
        int bh = bblk * NHEAD + h;
        int4 vv = *(const int4*)(vtile + vloc * 132 + gi * 8);
        *(int4*)(Vp + ((size_t)(bh * HD + d)) * SEQ + s0 + gi * 8) = vv;
    }
}

// ---------------- Flash attention v7 (reverted from v8): split-KV + LDS-staged K/V + in-register P ----------------
// 128 q rows/block, 4 waves x 32 rows, 4 blocks/CU. Denominator on the matrix
// pipe via all-ones B-fragment MFMA. R9 lesson: fatter q-tiles (256/block,
// 2 blocks/CU) REGRESS — this kernel needs >=4 light waves/SIMD of TLP.
__global__ __launch_bounds__(256, 4) void attn_kernel(
    const u16* __restrict__ Qb, const u16* __restrict__ Kb,
    const u16* __restrict__ Vp, u16* __restrict__ O0,
    u16* __restrict__ O1, float* __restrict__ Lp)
{
    __shared__ u16 kbuf[2][64 * 64];
    __shared__ u16 vbuf[2][64 * 64];
    int wave = threadIdx.x >> 6, lane = threadIdx.x & 63;
    int col = lane & 15, quad = lane >> 4;
    int g = blockIdx.x;
    int xcd = g & 7, slot = g >> 3;        // slot 0..127
    int bh = xcd * 4 + (slot >> 5);        // 0..31 (all work of one bh on one XCD)
    int rem = slot & 31;
    int split = rem >> 4;                  // 0..1
    int qt = rem & 15;                     // 0..15
    int q0 = qt * 128 + wave * 32;
    int kstart = split * 16;               // kt units of 64

    // staging: lane covers row=lane>>3 (of an 8-row slab), 16B group (lane&7),
    // XOR-swizzled source group gs = (lane&7)^(lane>>3)
    int srow = lane >> 3;
    int sgrp = (lane & 7) ^ srow;
    const u16* Kt0 = Kb + (size_t)bh * SEQ * HD;
    const u16* Vt0 = Vp + (size_t)bh * HD * SEQ;
    long soffK = (long)srow * HD + sgrp * 8;
    long soffV = (long)srow * SEQ + sgrp * 8;
    int r0 = wave * 16;                    // this wave stages rows r0..r0+15 of K and V

    // fragment-read lane offsets (LDS elems), swizzle-matched
    int rbase = col * 64;
    int sw0 = ((quad)     ^ (col & 7)) * 8;
    int sw1 = ((quad + 4) ^ (col & 7)) * 8;

    // all-ones bf16 B-fragment for the denominator MFMA
    union { u32 w[4]; int4 i; } onesu;
    onesu.w[0] = onesu.w[1] = onesu.w[2] = onesu.w[3] = 0x3F803F80u;
    bf16x8 ones = as_bf8(onesu.i);

    // Q as B-operand fragments (scale 1/8 pre-folded); one-time scattered load
    bf16x8 aq[2][2];
#pragma unroll
    for (int m = 0; m < 2; m++) {
        const u16* qbase = Qb + ((size_t)bh * SEQ + q0 + m * 16 + col) * HD + quad * 8;
        aq[m][0] = ld_bf8(qbase);
        aq[m][1] = ld_bf8(qbase + 32);
    }

    f32x4 o[2][4] = {};          // [q-frag][d-tile]; lane holds O[q=quad*4+r][d=col..]
    f32x4 ol[2] = {};            // denominator accumulator (row sums)

    // prefetch tile 0 into buffer 0
    {
        int kbase = kstart * 64;
        gload_lds16(Kt0 + (size_t)(kbase + r0) * HD + soffK,      kbuf[0] + r0 * 64);
        gload_lds16(Kt0 + (size_t)(kbase + r0 + 8) * HD + soffK,  kbuf[0] + (r0 + 8) * 64);
        gload_lds16(Vt0 + (size_t)r0 * SEQ + kbase + soffV,       vbuf[0] + r0 * 64);
        gload_lds16(Vt0 + (size_t)(r0 + 8) * SEQ + kbase + soffV, vbuf[0] + (r0 + 8) * 64);
    }

    for (int kt = 0; kt < 16; ++kt) {
        int cur = kt & 1;
        __syncthreads();
        if (kt + 1 < 16) {
            int kbase = (kstart + kt + 1) * 64;
            int nb = cur ^ 1;
            gload_lds16(Kt0 + (size_t)(kbase + r0) * HD + soffK,      kbuf[nb] + r0 * 64);
            gload_lds16(Kt0 + (size_t)(kbase + r0 + 8) * HD + soffK,  kbuf[nb] + (r0 + 8) * 64);
            gload_lds16(Vt0 + (size_t)r0 * SEQ + kbase + soffV,       vbuf[nb] + r0 * 64);
            gload_lds16(Vt0 + (size_t)(r0 + 8) * SEQ + kbase + soffV, vbuf[nb] + (r0 + 8) * 64);
        }
        const u16* kb = kbuf[cur];
        const u16* vb = vbuf[cur];
        bf16x8 kf[4][2];
#pragma unroll
        for (int t = 0; t < 4; t++) {
            kf[t][0] = ld_bf8(kb + t * 1024 + rbase + sw0);
            kf[t][1] = ld_bf8(kb + t * 1024 + rbase + sw1);
        }
        int4 vraw[4][2];
#pragma unroll
        for (int t = 0; t < 4; t++) {
            vraw[t][0] = *(const int4*)(vb + t * 1024 + rbase + sw0);
            vraw[t][1] = *(const int4*)(vb + t * 1024 + rbase + sw1);
        }
        // scores S^T = K*Q^T, exp, pack P into A-frags (in-lane)
        int4 pfrag[2][2];   // [q-frag][s-half]
#pragma unroll
        for (int m = 0; m < 2; m++) {
#pragma unroll
            for (int t = 0; t < 4; t++) {
                f32x4 sa = {};
                sa = mfma16(kf[t][0], aq[m][0], sa);
                sa = mfma16(kf[t][1], aq[m][1], sa);
                f32x4 p;
#pragma unroll
                for (int r = 0; r < 4; r++)
                    p[r] = __builtin_exp2f(__builtin_fmaf(sa[r], LOG2E, -SOFTMAX_SHIFT));
                u32 lo = pack_bf(p[0], p[1]);
                u32 hi = pack_bf(p[2], p[3]);
                if ((t & 1) == 0) { pfrag[m][t >> 1].x = (int)lo; pfrag[m][t >> 1].y = (int)hi; }
                else              { pfrag[m][t >> 1].z = (int)lo; pfrag[m][t >> 1].w = (int)hi; }
            }
        }
        // PV + denominator: O += P*V, ol += P*1 (matrix pipe)
#pragma unroll
        for (int m = 0; m < 2; m++) {
#pragma unroll
            for (int t = 0; t < 4; t++)
#pragma unroll
                for (int h = 0; h < 2; h++)
                    o[m][t] = mfma16(as_bf8(pfrag[m][h]), as_bf8(vraw[t][h]), o[m][t]);
            ol[m] = mfma16(as_bf8(pfrag[m][0]), ones, ol[m]);
            ol[m] = mfma16(as_bf8(pfrag[m][1]), ones, ol[m]);
        }
    }

    // partial epilogue: un-normalized O (bf16) + row denominators (fp32)
    u16* Op = split ? O1 : O0;
#pragma unroll
    for (int m = 0; m < 2; m++) {
#pragma unroll
        for (int r = 0; r < 4; r++) {
            int srow2 = q0 + m * 16 + quad * 4 + r;
            if (col == 0)
                Lp[(size_t)split * 32 * SEQ + (size_t)bh * SEQ + srow2] = ol[m][r];
#pragma unroll
            for (int t = 0; t < 4; t++)
                Op[((size_t)bh * SEQ + srow2) * HD + t * 16 + col] = f2bf(o[m][t][r]);
        }
    }
}

// ---------------- combine: At = (O0 + O1) / (l0 + l1), bf16 out in [b][s][h*64+d] layout ----------------
__global__ __launch_bounds__(256) void combine_kernel(
    const u16* __restrict__ O0, const u16* __restrict__ O1,
    const float* __restrict__ Lp, u16* __restrict__ At)
{
    int i = blockIdx.x * 256 + threadIdx.x;   // 0 .. 32*2048*16-1
    int dg = i & 15;                           // 4-d group
    int q = (i >> 4) & 2047;
    int bh = i >> 15;                          // 0..31
    size_t ob = ((size_t)bh * SEQ + q) * HD + dg * 4;
    ushort4 a = *(const ushort4*)(O0 + ob);
    ushort4 b = *(const ushort4*)(O1 + ob);
    float l = Lp[(size_t)bh * SEQ + q] + Lp[(size_t)32 * SEQ + (size_t)bh * SEQ + q];
    float inv = 1.f / l;
    int bb = bh >> 4, h = bh & 15;
    ushort4 o;
    o.x = f2bf((bf2f(a.x) + bf2f(b.x)) * inv);
    o.y = f2bf((bf2f(a.y) + bf2f(b.y)) * inv);
    o.z = f2bf((bf2f(a.z) + bf2f(b.z)) * inv);
    o.w = f2bf((bf2f(a.w) + bf2f(b.w)) * inv);
    *(ushort4*)(At + ((size_t)(bb * SEQ + q)) * D_MODEL + h * 64 + dg * 4) = o;
}

// ---------------- out proj, dbuf K-loop: out[4096][1024] = A * Bt^T + bias (fp32 out) ----------------
__global__ __launch_bounds__(256) void gemm_out_kernel(
    const u16* __restrict__ A, const u16* __restrict__ Bt, const float* __restrict__ bias,
    float* __restrict__ out)
{
    __shared__ u16 lA[2][128 * 32];
    __shared__ u16 lB[2][128 * 32];
    int w = threadIdx.x >> 6, l = threadIdx.x & 63;
    int col = l & 15, quad = l >> 4;
    int wm = w >> 1, wn = w & 1;
    int m0 = blockIdx.x * 128;
    int n0 = blockIdx.y * 128;
    int lrow = l >> 2;
    int lcol = (l & 3) * 8;

#pragma unroll
    for (int i = 0; i < 2; i++) {
        int slab = w * 32 + i * 16;
        gload_lds16(A  + (size_t)(m0 + slab + lrow) * 1024 + lcol, lA[0] + slab * 32);
        gload_lds16(Bt + (size_t)(n0 + slab + lrow) * 1024 + lcol, lB[0] + slab * 32);
    }

    f32x4 acc[4][4] = {};
    for (int it = 0; it < 32; ++it) {
        int cur = it & 1;
        __syncthreads();
        if (it + 1 < 32) {
            int k0 = (it + 1) * 32;
            int nb = cur ^ 1;
#pragma unroll
            for (int i = 0; i < 2; i++) {
                int slab = w * 32 + i * 16;
                gload_lds16(A  + (size_t)(m0 + slab + lrow) * 1024 + k0 + lcol, lA[nb] + slab * 32);
                gload_lds16(Bt + (size_t)(n0 + slab + lrow) * 1024 + k0 + lcol, lB[nb] + slab * 32);
            }
        }
        bf16x8 af[4], bfr[4];
#pragma unroll
        for (int i = 0; i < 4; i++)
            af[i] = ld_bf8(lA[cur] + (wm * 64 + i * 16 + col) * 32 + quad * 8);
#pragma unroll
        for (int j = 0; j < 4; j++)
            bfr[j] = ld_bf8(lB[cur] + (wn * 64 + j * 16 + col) * 32 + quad * 8);
#pragma unroll
        for (int i = 0; i < 4; i++)
#pragma unroll
            for (int j = 0; j < 4; j++)
                acc[i][j] = mfma16(af[i], bfr[j], acc[i][j]);
    }

#pragma unroll
    for (int i = 0; i < 4; i++) {
#pragma unroll
        for (int j = 0; j < 4; j++) {
            int cc = n0 + wn * 64 + j * 16 + col;
            float bv = bias[cc];
#pragma unroll
            for (int r = 0; r < 4; r++) {
                int row = m0 + wm * 64 + i * 16 + quad * 4 + r;
                out[(size_t)row * D_MODEL + cc] = acc[i][j][r] + bv;
            }
        }
    }
}

extern "C" void kernel_launch(void* const* d_in, const int* in_sizes, int n_in,
                              void* d_out, int out_size, void* d_ws, size_t ws_size,
                              hipStream_t stream) {
    const float* x     = (const float*)d_in[0];
    const float* W_qkv = (const float*)d_in[1];
    const float* b_qkv = (const float*)d_in[2];
    const float* W_out = (const float*)d_in[3];
    const float* b_out = (const float*)d_in[4];
    float* out = (float*)d_out;

    // Workspace overlays (43 MB <= 48 MB budget):
    //   [0,8)    Xb (cast input)   -> after gemm_qkv: O0 partial
    //   [8,16)   Wqkvt             -> after gemm_qkv: O1 partial
    //   [16,24)  Qb                -> after attn: At (combine output)
    //   [24,32)  Kb
    //   [32,40)  Vp (permuted V)
    //   [40,40.5) Lp (fp32 split denominators)
    //   [41,43)  Woutt (own slot so prep can run first)
    char* ws = (char*)d_ws;
    u16* Xb    = (u16*)(ws);
    u16* Wqkvt = (u16*)(ws + (8ull << 20));
    u16* Qb    = (u16*)(ws + (16ull << 20));
    u16* Kb    = (u16*)(ws + (24ull << 20));
    u16* Vp    = (u16*)(ws + (32ull << 20));
    u16* O0    = (u16*)(ws);
    u16* O1    = (u16*)(ws + (8ull << 20));
    float* Lp  = (float*)(ws + (40ull << 20));
    u16* Woutt = (u16*)(ws + (41ull << 20));
    u16* At    = (u16*)(ws + (16ull << 20));

    prep_kernel<<<dim3(5120), 256, 0, stream>>>(x, Xb, W_qkv, Wqkvt, W_out, Woutt);
    gemm_qkv_kernel<<<dim3(32, 24), 256, 0, stream>>>(Xb, Wqkvt, b_qkv, Qb, Kb, Vp);
    attn_kernel<<<dim3(1024), 256, 0, stream>>>(Qb, Kb, Vp, O0, O1, Lp);
    combine_kernel<<<dim3(BATCH * NHEAD * SEQ * (HD / 4) / 256), 256, 0, stream>>>(O0, O1, Lp, At);
    gemm_out_kernel<<<dim3(32, 8), 256, 0, stream>>>(At, Woutt, b_out, out);
}